// Round 15
// baseline (555.542 us; speedup 1.0000x reference)
//
#include <hip/hip_runtime.h>

#define NN  50000
#define NE  600000
#define CC  128
#define NFF 256
#define ECH 64
#define EIN 192   // ECH + CC

typedef __attribute__((ext_vector_type(8))) short bf16x8;
typedef __attribute__((ext_vector_type(4))) float f32x4;
typedef __attribute__((ext_vector_type(4))) unsigned u32x4;
typedef __attribute__((ext_vector_type(2))) unsigned u32x2;

// fast shifted-softplus: softplus(v)-ln2 via hw exp/log
__device__ __forceinline__ float sspf(float v) {
    float e = __expf(-fabsf(v));
    return fmaxf(v, 0.f) + __logf(1.f + e) - 0.693147180559945f;
}
// fast tanh via hw exp
__device__ __forceinline__ float ftanh(float v) {
    float e = __expf(-2.f * fabsf(v));
    float r = (1.f - e) / (1.f + e);
    return copysignf(r, v);
}
__device__ __forceinline__ short bf16r(float f) {
    unsigned u = __float_as_uint(f);
    u = (u + 0x7FFFu + ((u >> 16) & 1u)) >> 16;
    return (short)u;
}
// packed fp32x2 -> bf16x2 (RNE), single VALU op
__device__ __forceinline__ unsigned cvtpk(float lo, float hi) {
    unsigned r;
    asm("v_cvt_pk_bf16_f32 %0, %1, %2" : "=v"(r) : "v"(lo), "v"(hi));
    return r;
}
__device__ __forceinline__ float bfu_lo(unsigned u) { return __uint_as_float(u << 16); }
__device__ __forceinline__ float bfu_hi(unsigned u) { return __uint_as_float(u & 0xffff0000u); }

union cvu { u32x4 u; bf16x8 b; };

// ---- pack ALL weights to bf16 fragment-linear layout for mfma_16x16x32 B-op.
// 256-col tensors (h, t1, agg) live in fragment order p = w*64 + l15*4 + nf;
// consumers' k-dims packed with orig_k(p) = (p>>6)*64+(p&3)*16+((p>>2)&15).
// 128-col t2 (k3-internal): p2 order, orig_k2(p) = (p>>5)*32+(p&1)*16+((p&31)>>1).
#define PO_WF1 0
#define PO_WF2 16384
#define PO_WE  81920
#define PO_WL1 106496
#define PO_WL2 139264
#define PO_WL3 172032
#define P_TOT  188416
__global__ void kpack(const float* __restrict__ Wf1, const float* __restrict__ Wf2,
                      const float* __restrict__ We,  const float* __restrict__ Wl1,
                      const float* __restrict__ Wl2, const float* __restrict__ Wl3,
                      short* __restrict__ p) {
    int i = blockIdx.x * 256 + threadIdx.x;
    if (i < PO_WF2) {                      // Wf1 [64][256]: k orig, n orig
        int t = i - PO_WF1;
        int j = t & 7, lane = (t >> 3) & 63, n16 = (t >> 9) & 15, ks = t >> 13;
        p[i] = bf16r(Wf1[(ks * 32 + (lane >> 4) * 8 + j) * NFF + n16 * 16 + (lane & 15)]);
    } else if (i < PO_WE) {                // Wf2 [256][256]: k in t1 p-order
        int t = i - PO_WF2;
        int j = t & 7, lane = (t >> 3) & 63, n16 = (t >> 9) & 15, ks = t >> 13;
        int kp = ks * 32 + (lane >> 4) * 8 + j;
        int k = (kp >> 6) * 64 + (kp & 3) * 16 + ((kp >> 2) & 15);
        p[i] = bf16r(Wf2[k * NFF + n16 * 16 + (lane & 15)]);
    } else if (i < PO_WL1) {               // We [192][128]: k orig, n orig
        int t = i - PO_WE;
        int j = t & 7, lane = (t >> 3) & 63, n16 = (t >> 9) & 7, ks = t >> 12;
        p[i] = bf16r(We[(ks * 32 + (lane >> 4) * 8 + j) * CC + n16 * 16 + (lane & 15)]);
    } else if (i < PO_WL2) {               // Wl1 [128][256]: k orig, n orig
        int t = i - PO_WL1;
        int j = t & 7, lane = (t >> 3) & 63, n16 = (t >> 9) & 15, ks = t >> 13;
        p[i] = bf16r(Wl1[(ks * 32 + (lane >> 4) * 8 + j) * NFF + n16 * 16 + (lane & 15)]);
    } else if (i < PO_WL3) {               // Wl2 [256][128]: k in agg p-order
        int t = i - PO_WL2;
        int j = t & 7, lane = (t >> 3) & 63, n16 = (t >> 9) & 7, ks = t >> 12;
        int kp = ks * 32 + (lane >> 4) * 8 + j;
        int k = (kp >> 6) * 64 + (kp & 3) * 16 + ((kp >> 2) & 15);
        p[i] = bf16r(Wl2[k * CC + n16 * 16 + (lane & 15)]);
    } else if (i < P_TOT) {                // Wl3 [128][128]: k in t2 p2-order
        int t = i - PO_WL3;
        int j = t & 7, lane = (t >> 3) & 63, n16 = (t >> 9) & 7, ks = t >> 12;
        int kp = ks * 32 + (lane >> 4) * 8 + j;
        int k = (kp >> 5) * 32 + (kp & 1) * 16 + ((kp & 31) >> 1);
        p[i] = bf16r(Wl3[k * CC + n16 * 16 + (lane & 15)]);
    }
}

// ---- K0: zero two regions in one launch (grid-stride) ----
__global__ void k0_zero2(float* __restrict__ p0, long n40,
                         float* __restrict__ p1, long n41) {
    long i = (long)blockIdx.x * blockDim.x + threadIdx.x;
    long stride = (long)gridDim.x * blockDim.x;
    float4 z = {0.f, 0.f, 0.f, 0.f};
    for (long k = i; k < n40; k += stride) ((float4*)p0)[k] = z;
    for (long k = i; k < n41; k += stride) ((float4*)p1)[k] = z;
}

// ---- CSR build ----
__global__ void k_cnt(const int* __restrict__ eidx, int* __restrict__ cnt) {
    int e = blockIdx.x * 256 + threadIdx.x;
    if (e < NE) atomicAdd(&cnt[eidx[e]], 1);
}

// 3-phase scan (NB blocks of 256)
__global__ __launch_bounds__(256) void k_scan1(const int* __restrict__ cnt,
                                               int* __restrict__ offw,
                                               int* __restrict__ bsum) {
    __shared__ int sw_[4];
    int i = blockIdx.x * 256 + threadIdx.x;
    int lane = threadIdx.x & 63, wv = threadIdx.x >> 6;
    int v = (i < NN) ? cnt[i] : 0;
    int inc = v;
    #pragma unroll
    for (int d = 1; d < 64; d <<= 1) {
        int t = __shfl_up(inc, d, 64);
        if (lane >= d) inc += t;
    }
    if (lane == 63) sw_[wv] = inc;
    __syncthreads();
    int woff = 0;
    #pragma unroll
    for (int k = 0; k < 4; ++k) woff += (k < wv) ? sw_[k] : 0;
    if (i < NN) offw[i] = woff + inc - v;
    if (threadIdx.x == 255) bsum[blockIdx.x] = woff + inc;
}

__global__ __launch_bounds__(256) void k_scan2(int* __restrict__ bsum, int nb) {
    __shared__ int sw_[4];
    int t = threadIdx.x;
    int lane = t & 63, wv = t >> 6;
    int v = (t < nb) ? bsum[t] : 0;
    int inc = v;
    #pragma unroll
    for (int d = 1; d < 64; d <<= 1) {
        int s = __shfl_up(inc, d, 64);
        if (lane >= d) inc += s;
    }
    if (lane == 63) sw_[wv] = inc;
    __syncthreads();
    int woff = 0;
    #pragma unroll
    for (int k = 0; k < 4; ++k) woff += (k < wv) ? sw_[k] : 0;
    if (t < nb) bsum[t] = woff + inc - v;
}

__global__ void k_scan3(int* __restrict__ offw, const int* __restrict__ bsum) {
    int i = blockIdx.x * 256 + threadIdx.x;
    if (i < NN) offw[i] += bsum[blockIdx.x];
}

// ---- scatter: physically permute edges into row-sorted order (bf16 ea_s) ----
__global__ void k_scatter(const int* __restrict__ eidx, const float* __restrict__ ea,
                          int* __restrict__ offw, short* __restrict__ ea_s,
                          int* __restrict__ col_s, int* __restrict__ row_s) {
    int e = blockIdx.x * 256 + threadIdx.x;
    if (e >= NE) return;
    int r = eidx[e], c = eidx[NE + e];
    int pos = atomicAdd(&offw[r], 1);
    col_s[pos] = c;
    row_s[pos] = r;
    const float4* src = (const float4*)(ea + (size_t)e * ECH);
    short* dst = ea_s + (size_t)pos * ECH;
    #pragma unroll
    for (int i = 0; i < 4; ++i) {
        float4 f0 = src[4 * i], f1 = src[4 * i + 1], f2 = src[4 * i + 2], f3 = src[4 * i + 3];
        u32x4 v0 = {cvtpk(f0.x, f0.y), cvtpk(f0.z, f0.w), cvtpk(f1.x, f1.y), cvtpk(f1.z, f1.w)};
        u32x4 v1 = {cvtpk(f2.x, f2.y), cvtpk(f2.z, f2.w), cvtpk(f3.x, f3.y), cvtpk(f3.z, f3.w)};
        *(u32x4*)(dst + i * 16) = v0;
        *(u32x4*)(dst + i * 16 + 8) = v1;
    }
}

// ---- K1: h[N,256] = x @ Wl1 (MFMA), h stored in p-order ----
__global__ __launch_bounds__(256) void k1_h(const float* __restrict__ x,
                                            const short* __restrict__ pW,
                                            short* __restrict__ h) {
    __shared__ char xS[32 * 256];   // [32][128] bf16, swizzled
    int n0 = blockIdx.x * 32;
    int tid = threadIdx.x;
    int lane = tid & 63, w = tid >> 6, q = lane >> 4, l15 = lane & 15;
    {
        int r = tid >> 3, seg = tid & 7;
        int rr = min(n0 + r, NN - 1);
        const float4* src = (const float4*)(x + (size_t)rr * CC + seg * 16);
        float4 f0 = src[0], f1 = src[1], f2 = src[2], f3 = src[3];
        u32x4 c0 = {cvtpk(f0.x, f0.y), cvtpk(f0.z, f0.w), cvtpk(f1.x, f1.y), cvtpk(f1.z, f1.w)};
        u32x4 c1 = {cvtpk(f2.x, f2.y), cvtpk(f2.z, f2.w), cvtpk(f3.x, f3.y), cvtpk(f3.z, f3.w)};
        int sw = (r & 7) << 4;
        *(u32x4*)(xS + r * 256 + ((seg * 32) ^ sw)) = c0;
        *(u32x4*)(xS + r * 256 + ((seg * 32 + 16) ^ sw)) = c1;
    }
    __syncthreads();

    f32x4 acc[2][4];
    #pragma unroll
    for (int mf = 0; mf < 2; ++mf)
        #pragma unroll
        for (int nf = 0; nf < 4; ++nf) acc[mf][nf] = f32x4{0.f, 0.f, 0.f, 0.f};

    #pragma unroll
    for (int ks = 0; ks < 4; ++ks) {
        bf16x8 a[2];
        #pragma unroll
        for (int mf = 0; mf < 2; ++mf) {
            int row = mf * 16 + l15;
            a[mf] = *(const bf16x8*)(xS + row * 256 + ((ks * 64 + q * 16) ^ ((row & 7) << 4)));
        }
        #pragma unroll
        for (int nf = 0; nf < 4; ++nf) {
            bf16x8 b = *(const bf16x8*)(pW + PO_WL1 + (((ks * 16 + w * 4 + nf) * 64) + lane) * 8);
            #pragma unroll
            for (int mf = 0; mf < 2; ++mf)
                acc[mf][nf] = __builtin_amdgcn_mfma_f32_16x16x32_bf16(a[mf], b, acc[mf][nf], 0, 0, 0);
        }
    }
    #pragma unroll
    for (int mf = 0; mf < 2; ++mf) {
        #pragma unroll
        for (int r = 0; r < 4; ++r) {
            int n = n0 + mf * 16 + q * 4 + r;
            if (n < NN) {
                u32x2 v = {cvtpk(acc[mf][0][r], acc[mf][1][r]),
                           cvtpk(acc[mf][2][r], acc[mf][3][r])};
                *(u32x2*)(h + (size_t)n * NFF + w * 64 + l15 * 4) = v;
            }
        }
    }
}

// ---- K2b: FUSED filter-net + modulate + in-LDS segment-reduce -> agg fp32 ----
// 64 sorted slots/block, 4 waves; wave w owns cols [w*64, w*64+64).
// Walk: ALL 256 threads; 2 threads per col-pair, 32 slots each.
__global__ __launch_bounds__(256, 4) void k2b_agg(
        const short* __restrict__ ea_s, const int* __restrict__ col_s,
        const int* __restrict__ row_s,
        const short* __restrict__ pW, const float* __restrict__ bf1v,
        const float* __restrict__ bf2v,
        const short* __restrict__ h, float* __restrict__ agg) {
    __shared__ char t1S[64 * 512];   // t1 p-order -> h rows -> msg tile (in place)
    __shared__ int colS[64], rowS[64];
    int s0 = blockIdx.x * 64;
    int tid = threadIdx.x;
    int lane = tid & 63, w = tid >> 6;
    int q = lane >> 4, l15 = lane & 15;

    if (tid < 64) {
        colS[tid] = col_s[s0 + tid];
        rowS[tid] = row_s[s0 + tid];
    }

    f32x4 acc[4][4];
    #pragma unroll
    for (int mf = 0; mf < 4; ++mf)
        #pragma unroll
        for (int nf = 0; nf < 4; ++nf) acc[mf][nf] = f32x4{0.f, 0.f, 0.f, 0.f};

    // phase 1: t1 = ssp(ea_s @ Wf1 + b1), K=64, M=64; A direct from global bf16
    #pragma unroll
    for (int ks = 0; ks < 2; ++ks) {
        bf16x8 a[4];
        #pragma unroll
        for (int mf = 0; mf < 4; ++mf)
            a[mf] = *(const bf16x8*)(ea_s + (size_t)(s0 + mf * 16 + l15) * ECH + ks * 32 + q * 8);
        #pragma unroll
        for (int nf = 0; nf < 4; ++nf) {
            bf16x8 b = *(const bf16x8*)(pW + PO_WF1 + (((ks * 16 + w * 4 + nf) * 64) + lane) * 8);
            #pragma unroll
            for (int mf = 0; mf < 4; ++mf)
                acc[mf][nf] = __builtin_amdgcn_mfma_f32_16x16x32_bf16(a[mf], b, acc[mf][nf], 0, 0, 0);
        }
    }
    // ssp + bias, write t1 in p-order: b64 per (mf,r)
    {
        float bia[4];
        #pragma unroll
        for (int nf = 0; nf < 4; ++nf) bia[nf] = bf1v[w * 64 + nf * 16 + l15];
        #pragma unroll
        for (int mf = 0; mf < 4; ++mf) {
            #pragma unroll
            for (int r = 0; r < 4; ++r) {
                int row = mf * 16 + q * 4 + r;
                u32x2 v = {cvtpk(sspf(acc[mf][0][r] + bia[0]), sspf(acc[mf][1][r] + bia[1])),
                           cvtpk(sspf(acc[mf][2][r] + bia[2]), sspf(acc[mf][3][r] + bia[3]))};
                *(u32x2*)(t1S + row * 512 + ((w * 128 + l15 * 8) ^ ((row & 7) << 4))) = v;
            }
        }
    }
    __syncthreads();

    #pragma unroll
    for (int mf = 0; mf < 4; ++mf)
        #pragma unroll
        for (int nf = 0; nf < 4; ++nf) acc[mf][nf] = f32x4{0.f, 0.f, 0.f, 0.f};

    // phase 2: Wf = t1 @ Wf2 + b2, K=256, M=64 (k in p-order)
    for (int ks = 0; ks < 8; ++ks) {
        bf16x8 a[4];
        #pragma unroll
        for (int mf = 0; mf < 4; ++mf) {
            int row = mf * 16 + l15;
            a[mf] = *(const bf16x8*)(t1S + row * 512 + ((ks * 64 + q * 16) ^ ((row & 7) << 4)));
        }
        #pragma unroll
        for (int nf = 0; nf < 4; ++nf) {
            bf16x8 b = *(const bf16x8*)(pW + PO_WF2 + (((ks * 16 + w * 4 + nf) * 64) + lane) * 8);
            #pragma unroll
            for (int mf = 0; mf < 4; ++mf)
                acc[mf][nf] = __builtin_amdgcn_mfma_f32_16x16x32_bf16(a[mf], b, acc[mf][nf], 0, 0, 0);
        }
    }
    __syncthreads();   // t1S reads done; reuse region for h rows

    {   // stage h[colS[0..63]] (p-order rows) into LDS: 4 thr/row, 8x16B each
        int r = tid >> 2, ch = tid & 3;
        const short* hp = h + (size_t)colS[r] * NFF;
        int sw = (r & 7) << 4;
        #pragma unroll
        for (int i = 0; i < 8; ++i) {
            int chunk = ch + i * 4;
            bf16x8 v = *(const bf16x8*)(hp + chunk * 8);
            *(bf16x8*)(t1S + r * 512 + ((chunk * 16) ^ sw)) = v;
        }
    }
    __syncthreads();

    // in-place modulate: t1S[eloc][p-pair] = h * Wf  (each addr owned by one thread)
    {
        float bia[4];
        #pragma unroll
        for (int nf = 0; nf < 4; ++nf) bia[nf] = bf2v[w * 64 + nf * 16 + l15];
        #pragma unroll
        for (int mf = 0; mf < 4; ++mf) {
            #pragma unroll
            for (int r = 0; r < 4; ++r) {
                int eloc = mf * 16 + q * 4 + r;
                char* addr = t1S + eloc * 512 + ((w * 128 + l15 * 8) ^ ((eloc & 7) << 4));
                u32x2 hv = *(const u32x2*)addr;
                float m0 = bfu_lo(hv[0]) * (acc[mf][0][r] + bia[0]);
                float m1 = bfu_hi(hv[0]) * (acc[mf][1][r] + bia[1]);
                float m2 = bfu_lo(hv[1]) * (acc[mf][2][r] + bia[2]);
                float m3 = bfu_hi(hv[1]) * (acc[mf][3][r] + bia[3]);
                u32x2 out = {cvtpk(m0, m1), cvtpk(m2, m3)};
                *(u32x2*)addr = out;
            }
        }
    }
    __syncthreads();

    // segment-reduce: ALL 256 threads. thread = (half, cp): cp = tid&127 owns
    // cols (2cp, 2cp+1) in p-order; half = tid>>7 walks slots [half*32, half*32+32).
    {
        int cp = tid & 127;
        int h0 = (tid >> 7) * 32;
        float a0 = 0.f, a1 = 0.f;
        int cur = rowS[h0];
        bool first = true;
        for (int e = h0; e < h0 + 32; ++e) {
            int rw = rowS[e];
            if (rw != cur) {
                float* dst = agg + (size_t)cur * NFF + cp * 2;
                if (first) { atomicAdd(dst, a0); atomicAdd(dst + 1, a1); first = false; }
                else       { dst[0] = a0; dst[1] = a1; }
                a0 = 0.f; a1 = 0.f;
                cur = rw;
            }
            unsigned v = *(const unsigned*)(t1S + e * 512 + ((cp * 4) ^ ((e & 7) << 4)));
            a0 += bfu_lo(v);
            a1 += bfu_hi(v);
        }
        float* dst = agg + (size_t)cur * NFF + cp * 2;
        atomicAdd(dst, a0); atomicAdd(dst + 1, a1);
    }
}

// ---- K3: load agg (fp32, p-order) + MFMA node GEMMs ----
__global__ __launch_bounds__(256) void k3_node(
        const float* __restrict__ agg,
        const short* __restrict__ pW, const float* __restrict__ bl2,
        const float* __restrict__ bl3,
        const float* __restrict__ x, float* __restrict__ xo) {
    __shared__ char aggS[32 * 512];  // [32][256] bf16 p-order, swizzled
    __shared__ char t2S[32 * 256];   // [32][128] bf16 p2-order, swizzled
    int n0 = blockIdx.x * 32;
    int tid = threadIdx.x;
    int lane = tid & 63, w = tid >> 6, q = lane >> 4, l15 = lane & 15;

    {   // coalesced agg load: 8 thr/node, 32 cols each
        int nd = tid >> 3, c0 = (tid & 7) * 32;
        int n = n0 + nd;
        float a[32];
        if (n < NN) {
            const float4* src = (const float4*)(agg + (size_t)n * NFF + c0);
            #pragma unroll
            for (int j = 0; j < 8; ++j) {
                float4 v = src[j];
                a[4 * j] = v.x; a[4 * j + 1] = v.y; a[4 * j + 2] = v.z; a[4 * j + 3] = v.w;
            }
        } else {
            #pragma unroll
            for (int i = 0; i < 32; ++i) a[i] = 0.f;
        }
        int sw = (nd & 7) << 4;
        #pragma unroll
        for (int j = 0; j < 4; ++j) {
            u32x4 v = {cvtpk(a[j * 8 + 0], a[j * 8 + 1]), cvtpk(a[j * 8 + 2], a[j * 8 + 3]),
                       cvtpk(a[j * 8 + 4], a[j * 8 + 5]), cvtpk(a[j * 8 + 6], a[j * 8 + 7])};
            *(u32x4*)(aggS + nd * 512 + (((c0 + j * 8) * 2) ^ sw)) = v;
        }
    }
    __syncthreads();

    // GEMM1: t2 = ssp(agg @ Wl2 + b2), k in p-order (pWl2 matches)
    f32x4 acc[2][2];
    #pragma unroll
    for (int mf = 0; mf < 2; ++mf)
        #pragma unroll
        for (int nf = 0; nf < 2; ++nf) acc[mf][nf] = f32x4{0.f, 0.f, 0.f, 0.f};
    for (int ks = 0; ks < 8; ++ks) {
        bf16x8 a[2];
        #pragma unroll
        for (int mf = 0; mf < 2; ++mf) {
            int row = mf * 16 + l15;
            a[mf] = *(const bf16x8*)(aggS + row * 512 + ((ks * 64 + q * 16) ^ ((row & 7) << 4)));
        }
        #pragma unroll
        for (int nf = 0; nf < 2; ++nf) {
            bf16x8 b = *(const bf16x8*)(pW + PO_WL2 + (((ks * 8 + w * 2 + nf) * 64) + lane) * 8);
            #pragma unroll
            for (int mf = 0; mf < 2; ++mf)
                acc[mf][nf] = __builtin_amdgcn_mfma_f32_16x16x32_bf16(a[mf], b, acc[mf][nf], 0, 0, 0);
        }
    }
    {   // t2 in p2-order: b32 per (mf,r)
        float bia[2];
        #pragma unroll
        for (int nf = 0; nf < 2; ++nf) bia[nf] = bl2[w * 32 + nf * 16 + l15];
        #pragma unroll
        for (int mf = 0; mf < 2; ++mf) {
            #pragma unroll
            for (int r = 0; r < 4; ++r) {
                int row = mf * 16 + q * 4 + r;
                unsigned u = cvtpk(sspf(acc[mf][0][r] + bia[0]), sspf(acc[mf][1][r] + bia[1]));
                *(unsigned*)(t2S + row * 256 + ((w * 64 + l15 * 4) ^ ((row & 7) << 4))) = u;
            }
        }
    }
    __syncthreads();

    // GEMM2: y = t2 @ Wl3 + b3, k in p2-order (pWl3 matches)
    f32x4 acc2[2][2];
    #pragma unroll
    for (int mf = 0; mf < 2; ++mf)
        #pragma unroll
        for (int nf = 0; nf < 2; ++nf) acc2[mf][nf] = f32x4{0.f, 0.f, 0.f, 0.f};
    #pragma unroll
    for (int ks = 0; ks < 4; ++ks) {
        bf16x8 a[2];
        #pragma unroll
        for (int mf = 0; mf < 2; ++mf) {
            int row = mf * 16 + l15;
            a[mf] = *(const bf16x8*)(t2S + row * 256 + ((ks * 64 + q * 16) ^ ((row & 7) << 4)));
        }
        #pragma unroll
        for (int nf = 0; nf < 2; ++nf) {
            bf16x8 b = *(const bf16x8*)(pW + PO_WL3 + (((ks * 8 + w * 2 + nf) * 64) + lane) * 8);
            #pragma unroll
            for (int mf = 0; mf < 2; ++mf)
                acc2[mf][nf] = __builtin_amdgcn_mfma_f32_16x16x32_bf16(a[mf], b, acc2[mf][nf], 0, 0, 0);
        }
    }
    #pragma unroll
    for (int nf = 0; nf < 2; ++nf) {
        int col = w * 32 + nf * 16 + l15;
        float bias = bl3[col];
        #pragma unroll
        for (int mf = 0; mf < 2; ++mf) {
            #pragma unroll
            for (int r = 0; r < 4; ++r) {
                int n = n0 + mf * 16 + q * 4 + r;
                if (n < NN) {
                    size_t o = (size_t)n * CC + col;
                    xo[o] = fmaxf(acc2[mf][nf][r] + bias, 0.f) + x[o];
                }
            }
        }
    }
}

// ---- K4: MFMA e_out = tanh([ea | xo[row]+xo[col]] @ We + be) ----
// ea streamed with NT loads; eo written with NT stores (keep xo cache-resident).
__global__ __launch_bounds__(256) void k4_mfma(
        const float* __restrict__ ea, const int* __restrict__ eidx,
        const float* __restrict__ xo, const short* __restrict__ pW,
        const float* __restrict__ bev, float* __restrict__ eo) {
    __shared__ char aS[64 * 256];    // [64][128] bf16 (xo-sum part), swizzled
    int e0 = blockIdx.x * 64;
    int tid = threadIdx.x;
    int lane = tid & 63, w = tid >> 6;
    int q = lane >> 4, l15 = lane & 15;

    {   // stage xo[row]+xo[col] (k 64..191)
        int e = tid >> 2, p = tid & 3;
        int rr = eidx[e0 + e], cc = eidx[NE + e0 + e];
        const float4* xr = (const float4*)(xo + (size_t)rr * CC);
        const float4* xc = (const float4*)(xo + (size_t)cc * CC);
        int sw = (e & 7) << 4;
        #pragma unroll
        for (int it = 0; it < 8; ++it) {
            int fi = p + it * 4;
            float4 va = xr[fi], vb = xc[fi];
            u32x2 hv = {cvtpk(va.x + vb.x, va.y + vb.y), cvtpk(va.z + vb.z, va.w + vb.w)};
            *(u32x2*)(aS + e * 256 + ((fi * 8) ^ sw)) = hv;
        }
    }
    __syncthreads();

    f32x4 acc[8];
    #pragma unroll
    for (int nf = 0; nf < 8; ++nf) acc[nf] = f32x4{0.f, 0.f, 0.f, 0.f};

    int row = w * 16 + l15;
    // ks 0..1: A from global ea (fp32 -> bf16 in regs), non-temporal stream
    #pragma unroll
    for (int ks = 0; ks < 2; ++ks) {
        const f32x4* src = (const f32x4*)(ea + (size_t)(e0 + row) * ECH + ks * 32 + q * 8);
        f32x4 f0 = __builtin_nontemporal_load(src);
        f32x4 f1 = __builtin_nontemporal_load(src + 1);
        cvu cv;
        cv.u = u32x4{cvtpk(f0[0], f0[1]), cvtpk(f0[2], f0[3]),
                     cvtpk(f1[0], f1[1]), cvtpk(f1[2], f1[3])};
        bf16x8 a = cv.b;
        #pragma unroll
        for (int nf = 0; nf < 8; ++nf) {
            bf16x8 b = *(const bf16x8*)(pW + PO_WE + (((ks * 8 + nf) * 64) + lane) * 8);
            acc[nf] = __builtin_amdgcn_mfma_f32_16x16x32_bf16(a, b, acc[nf], 0, 0, 0);
        }
    }
    // ks 2..5: A from LDS (xo-sum part; local k index 0..127)
    #pragma unroll
    for (int ks = 2; ks < 6; ++ks) {
        bf16x8 a = *(const bf16x8*)(aS + row * 256 + (((ks - 2) * 64 + q * 16) ^ ((row & 7) << 4)));
        #pragma unroll
        for (int nf = 0; nf < 8; ++nf) {
            bf16x8 b = *(const bf16x8*)(pW + PO_WE + (((ks * 8 + nf) * 64) + lane) * 8);
            acc[nf] = __builtin_amdgcn_mfma_f32_16x16x32_bf16(a, b, acc[nf], 0, 0, 0);
        }
    }
    #pragma unroll
    for (int nf = 0; nf < 8; ++nf) {
        int col = nf * 16 + l15;
        float bias = bev[col];
        #pragma unroll
        for (int r = 0; r < 4; ++r) {
            int e = e0 + w * 16 + q * 4 + r;
            __builtin_nontemporal_store(ftanh(acc[nf][r] + bias),
                                        &eo[(size_t)e * CC + col]);
        }
    }
}

extern "C" void kernel_launch(void* const* d_in, const int* in_sizes, int n_in,
                              void* d_out, int out_size, void* d_ws, size_t ws_size,
                              hipStream_t stream) {
    const float* x   = (const float*)d_in[0];
    const int*   ei  = (const int*)d_in[1];
    const float* ea  = (const float*)d_in[2];
    const float* Wf1 = (const float*)d_in[4];
    const float* bf1 = (const float*)d_in[5];
    const float* Wf2 = (const float*)d_in[6];
    const float* bf2 = (const float*)d_in[7];
    const float* Wl1 = (const float*)d_in[8];
    const float* Wl2 = (const float*)d_in[9];
    const float* bl2 = (const float*)d_in[10];
    const float* Wl3 = (const float*)d_in[11];
    const float* bl3 = (const float*)d_in[12];
    const float* We  = (const float*)d_in[13];
    const float* be  = (const float*)d_in[14];

    float* xo = (float*)d_out;                 // [N, C] final
    float* eo = xo + (size_t)NN * CC;          // [E, C] final

    // region reuse (sequential lifetimes, fully rewritten each call):
    //   h    bf16 [N,256] p-order in the xo region (dead before k3 writes xo)
    //   ea_s/col_s/row_s/agg carved from the TAIL of the eo region
    //   (all dead before k4 writes eo; k3 reads agg before k4 runs)
    short* h    = (short*)xo;                                  // 25.6 MB
    char*  top  = (char*)d_out + (size_t)out_size * sizeof(float);
    short* ea_s = (short*)(top - (size_t)NE * ECH * 2);        // 76.8 MB
    int*   col_s = (int*)((char*)ea_s - (size_t)NE * 4);       // 2.4 MB
    int*   row_s = (int*)((char*)col_s - (size_t)NE * 4);      // 2.4 MB
    float* agg  = (float*)((char*)row_s - (size_t)NN * NFF * 4); // 51.2 MB

    // ws: [packed weights 384KB][cnt N][offw N][bsum 256]
    short* pW    = (short*)d_ws;
    int* cnt     = (int*)((char*)d_ws + 393216);
    int* offw    = cnt + NN;
    int* bsum    = offw + NN;

    const int NB = (NN + 255) / 256;

    kpack<<<P_TOT / 256, 256, 0, stream>>>(Wf1, Wf2, We, Wl1, Wl2, Wl3, pW);
    k0_zero2<<<1024, 256, 0, stream>>>(agg, (long)NN * NFF / 4, (float*)cnt, NN / 4);
    k_cnt<<<(NE + 255) / 256, 256, 0, stream>>>(ei, cnt);
    k_scan1<<<NB, 256, 0, stream>>>(cnt, offw, bsum);
    k_scan2<<<1, 256, 0, stream>>>(bsum, NB);
    k_scan3<<<NB, 256, 0, stream>>>(offw, bsum);
    k_scatter<<<(NE + 255) / 256, 256, 0, stream>>>(ei, ea, offw, ea_s, col_s, row_s);
    k1_h<<<(NN + 31) / 32, 256, 0, stream>>>(x, pW, h);
    k2b_agg<<<NE / 64, 256, 0, stream>>>(ea_s, col_s, row_s, pW, bf1, bf2, h, agg);
    k3_node<<<(NN + 31) / 32, 256, 0, stream>>>(agg, pW, bl2, bl3, x, xo);
    k4_mfma<<<NE / 64, 256, 0, stream>>>(ea, ei, xo, pW, be, eo);
}

// Round 16
// 541.472 us; speedup vs baseline: 1.0260x; 1.0260x over previous
//
#include <hip/hip_runtime.h>

#define NN  50000
#define NE  600000
#define CC  128
#define NFF 256
#define ECH 64
#define EIN 192   // ECH + CC

typedef __attribute__((ext_vector_type(8))) short bf16x8;
typedef __attribute__((ext_vector_type(4))) float f32x4;
typedef __attribute__((ext_vector_type(4))) unsigned u32x4;
typedef __attribute__((ext_vector_type(2))) unsigned u32x2;

// fast shifted-softplus: softplus(v)-ln2 via hw exp/log
__device__ __forceinline__ float sspf(float v) {
    float e = __expf(-fabsf(v));
    return fmaxf(v, 0.f) + __logf(1.f + e) - 0.693147180559945f;
}
// fast tanh via hw exp
__device__ __forceinline__ float ftanh(float v) {
    float e = __expf(-2.f * fabsf(v));
    float r = (1.f - e) / (1.f + e);
    return copysignf(r, v);
}
__device__ __forceinline__ short bf16r(float f) {
    unsigned u = __float_as_uint(f);
    u = (u + 0x7FFFu + ((u >> 16) & 1u)) >> 16;
    return (short)u;
}
// packed fp32x2 -> bf16x2 (RNE), single VALU op
__device__ __forceinline__ unsigned cvtpk(float lo, float hi) {
    unsigned r;
    asm("v_cvt_pk_bf16_f32 %0, %1, %2" : "=v"(r) : "v"(lo), "v"(hi));
    return r;
}
__device__ __forceinline__ float bfu_lo(unsigned u) { return __uint_as_float(u << 16); }
__device__ __forceinline__ float bfu_hi(unsigned u) { return __uint_as_float(u & 0xffff0000u); }

union cvu { u32x4 u; bf16x8 b; };

// ---- pack ALL weights to bf16 fragment-linear layout for mfma_16x16x32 B-op.
// 256-col tensors (h, t1, agg) live in fragment order p = w*64 + l15*4 + nf;
// consumers' k-dims packed with orig_k(p) = (p>>6)*64+(p&3)*16+((p>>2)&15).
// 128-col t2 (k3-internal): p2 order, orig_k2(p) = (p>>5)*32+(p&1)*16+((p&31)>>1).
#define PO_WF1 0
#define PO_WF2 16384
#define PO_WE  81920
#define PO_WL1 106496
#define PO_WL2 139264
#define PO_WL3 172032
#define P_TOT  188416
__global__ void kpack(const float* __restrict__ Wf1, const float* __restrict__ Wf2,
                      const float* __restrict__ We,  const float* __restrict__ Wl1,
                      const float* __restrict__ Wl2, const float* __restrict__ Wl3,
                      short* __restrict__ p) {
    int i = blockIdx.x * 256 + threadIdx.x;
    if (i < PO_WF2) {                      // Wf1 [64][256]: k orig, n orig
        int t = i - PO_WF1;
        int j = t & 7, lane = (t >> 3) & 63, n16 = (t >> 9) & 15, ks = t >> 13;
        p[i] = bf16r(Wf1[(ks * 32 + (lane >> 4) * 8 + j) * NFF + n16 * 16 + (lane & 15)]);
    } else if (i < PO_WE) {                // Wf2 [256][256]: k in t1 p-order
        int t = i - PO_WF2;
        int j = t & 7, lane = (t >> 3) & 63, n16 = (t >> 9) & 15, ks = t >> 13;
        int kp = ks * 32 + (lane >> 4) * 8 + j;
        int k = (kp >> 6) * 64 + (kp & 3) * 16 + ((kp >> 2) & 15);
        p[i] = bf16r(Wf2[k * NFF + n16 * 16 + (lane & 15)]);
    } else if (i < PO_WL1) {               // We [192][128]: k orig, n orig
        int t = i - PO_WE;
        int j = t & 7, lane = (t >> 3) & 63, n16 = (t >> 9) & 7, ks = t >> 12;
        p[i] = bf16r(We[(ks * 32 + (lane >> 4) * 8 + j) * CC + n16 * 16 + (lane & 15)]);
    } else if (i < PO_WL2) {               // Wl1 [128][256]: k orig, n orig
        int t = i - PO_WL1;
        int j = t & 7, lane = (t >> 3) & 63, n16 = (t >> 9) & 15, ks = t >> 13;
        p[i] = bf16r(Wl1[(ks * 32 + (lane >> 4) * 8 + j) * NFF + n16 * 16 + (lane & 15)]);
    } else if (i < PO_WL3) {               // Wl2 [256][128]: k in agg p-order
        int t = i - PO_WL2;
        int j = t & 7, lane = (t >> 3) & 63, n16 = (t >> 9) & 7, ks = t >> 12;
        int kp = ks * 32 + (lane >> 4) * 8 + j;
        int k = (kp >> 6) * 64 + (kp & 3) * 16 + ((kp >> 2) & 15);
        p[i] = bf16r(Wl2[k * CC + n16 * 16 + (lane & 15)]);
    } else if (i < P_TOT) {                // Wl3 [128][128]: k in t2 p2-order
        int t = i - PO_WL3;
        int j = t & 7, lane = (t >> 3) & 63, n16 = (t >> 9) & 7, ks = t >> 12;
        int kp = ks * 32 + (lane >> 4) * 8 + j;
        int k = (kp >> 5) * 32 + (kp & 1) * 16 + ((kp & 31) >> 1);
        p[i] = bf16r(Wl3[k * CC + n16 * 16 + (lane & 15)]);
    }
}

// ---- K0: zero two regions in one launch (grid-stride) ----
__global__ void k0_zero2(float* __restrict__ p0, long n40,
                         float* __restrict__ p1, long n41) {
    long i = (long)blockIdx.x * blockDim.x + threadIdx.x;
    long stride = (long)gridDim.x * blockDim.x;
    float4 z = {0.f, 0.f, 0.f, 0.f};
    for (long k = i; k < n40; k += stride) ((float4*)p0)[k] = z;
    for (long k = i; k < n41; k += stride) ((float4*)p1)[k] = z;
}

// ---- CSR build ----
__global__ void k_cnt(const int* __restrict__ eidx, int* __restrict__ cnt) {
    int e = blockIdx.x * 256 + threadIdx.x;
    if (e < NE) atomicAdd(&cnt[eidx[e]], 1);
}

// 3-phase scan (NB blocks of 256)
__global__ __launch_bounds__(256) void k_scan1(const int* __restrict__ cnt,
                                               int* __restrict__ offw,
                                               int* __restrict__ bsum) {
    __shared__ int sw_[4];
    int i = blockIdx.x * 256 + threadIdx.x;
    int lane = threadIdx.x & 63, wv = threadIdx.x >> 6;
    int v = (i < NN) ? cnt[i] : 0;
    int inc = v;
    #pragma unroll
    for (int d = 1; d < 64; d <<= 1) {
        int t = __shfl_up(inc, d, 64);
        if (lane >= d) inc += t;
    }
    if (lane == 63) sw_[wv] = inc;
    __syncthreads();
    int woff = 0;
    #pragma unroll
    for (int k = 0; k < 4; ++k) woff += (k < wv) ? sw_[k] : 0;
    if (i < NN) offw[i] = woff + inc - v;
    if (threadIdx.x == 255) bsum[blockIdx.x] = woff + inc;
}

__global__ __launch_bounds__(256) void k_scan2(int* __restrict__ bsum, int nb) {
    __shared__ int sw_[4];
    int t = threadIdx.x;
    int lane = t & 63, wv = t >> 6;
    int v = (t < nb) ? bsum[t] : 0;
    int inc = v;
    #pragma unroll
    for (int d = 1; d < 64; d <<= 1) {
        int s = __shfl_up(inc, d, 64);
        if (lane >= d) inc += s;
    }
    if (lane == 63) sw_[wv] = inc;
    __syncthreads();
    int woff = 0;
    #pragma unroll
    for (int k = 0; k < 4; ++k) woff += (k < wv) ? sw_[k] : 0;
    if (t < nb) bsum[t] = woff + inc - v;
}

__global__ void k_scan3(int* __restrict__ offw, const int* __restrict__ bsum) {
    int i = blockIdx.x * 256 + threadIdx.x;
    if (i < NN) offw[i] += bsum[blockIdx.x];
}

// ---- scatter: physically permute edges into row-sorted order (bf16 ea_s) ----
__global__ void k_scatter(const int* __restrict__ eidx, const float* __restrict__ ea,
                          int* __restrict__ offw, short* __restrict__ ea_s,
                          int* __restrict__ col_s, int* __restrict__ row_s,
                          int* __restrict__ perm_s) {
    int e = blockIdx.x * 256 + threadIdx.x;
    if (e >= NE) return;
    int r = eidx[e], c = eidx[NE + e];
    int pos = atomicAdd(&offw[r], 1);
    col_s[pos] = c;
    row_s[pos] = r;
    perm_s[pos] = e;
    const float4* src = (const float4*)(ea + (size_t)e * ECH);
    short* dst = ea_s + (size_t)pos * ECH;
    #pragma unroll
    for (int i = 0; i < 4; ++i) {
        float4 f0 = src[4 * i], f1 = src[4 * i + 1], f2 = src[4 * i + 2], f3 = src[4 * i + 3];
        u32x4 v0 = {cvtpk(f0.x, f0.y), cvtpk(f0.z, f0.w), cvtpk(f1.x, f1.y), cvtpk(f1.z, f1.w)};
        u32x4 v1 = {cvtpk(f2.x, f2.y), cvtpk(f2.z, f2.w), cvtpk(f3.x, f3.y), cvtpk(f3.z, f3.w)};
        *(u32x4*)(dst + i * 16) = v0;
        *(u32x4*)(dst + i * 16 + 8) = v1;
    }
}

// ---- K1: h[N,256] = x @ Wl1 (MFMA), h stored in p-order ----
__global__ __launch_bounds__(256) void k1_h(const float* __restrict__ x,
                                            const short* __restrict__ pW,
                                            short* __restrict__ h) {
    __shared__ char xS[32 * 256];   // [32][128] bf16, swizzled
    int n0 = blockIdx.x * 32;
    int tid = threadIdx.x;
    int lane = tid & 63, w = tid >> 6, q = lane >> 4, l15 = lane & 15;
    {
        int r = tid >> 3, seg = tid & 7;
        int rr = min(n0 + r, NN - 1);
        const float4* src = (const float4*)(x + (size_t)rr * CC + seg * 16);
        float4 f0 = src[0], f1 = src[1], f2 = src[2], f3 = src[3];
        u32x4 c0 = {cvtpk(f0.x, f0.y), cvtpk(f0.z, f0.w), cvtpk(f1.x, f1.y), cvtpk(f1.z, f1.w)};
        u32x4 c1 = {cvtpk(f2.x, f2.y), cvtpk(f2.z, f2.w), cvtpk(f3.x, f3.y), cvtpk(f3.z, f3.w)};
        int sw = (r & 7) << 4;
        *(u32x4*)(xS + r * 256 + ((seg * 32) ^ sw)) = c0;
        *(u32x4*)(xS + r * 256 + ((seg * 32 + 16) ^ sw)) = c1;
    }
    __syncthreads();

    f32x4 acc[2][4];
    #pragma unroll
    for (int mf = 0; mf < 2; ++mf)
        #pragma unroll
        for (int nf = 0; nf < 4; ++nf) acc[mf][nf] = f32x4{0.f, 0.f, 0.f, 0.f};

    #pragma unroll
    for (int ks = 0; ks < 4; ++ks) {
        bf16x8 a[2];
        #pragma unroll
        for (int mf = 0; mf < 2; ++mf) {
            int row = mf * 16 + l15;
            a[mf] = *(const bf16x8*)(xS + row * 256 + ((ks * 64 + q * 16) ^ ((row & 7) << 4)));
        }
        #pragma unroll
        for (int nf = 0; nf < 4; ++nf) {
            bf16x8 b = *(const bf16x8*)(pW + PO_WL1 + (((ks * 16 + w * 4 + nf) * 64) + lane) * 8);
            #pragma unroll
            for (int mf = 0; mf < 2; ++mf)
                acc[mf][nf] = __builtin_amdgcn_mfma_f32_16x16x32_bf16(a[mf], b, acc[mf][nf], 0, 0, 0);
        }
    }
    #pragma unroll
    for (int mf = 0; mf < 2; ++mf) {
        #pragma unroll
        for (int r = 0; r < 4; ++r) {
            int n = n0 + mf * 16 + q * 4 + r;
            if (n < NN) {
                u32x2 v = {cvtpk(acc[mf][0][r], acc[mf][1][r]),
                           cvtpk(acc[mf][2][r], acc[mf][3][r])};
                *(u32x2*)(h + (size_t)n * NFF + w * 64 + l15 * 4) = v;
            }
        }
    }
}

// ---- K2b: FUSED filter-net + modulate + in-LDS segment-reduce -> agg fp32 ----
// 64 sorted slots/block, 4 waves; wave w owns cols [w*64, w*64+64).
// Walk: ALL 256 threads; 2 threads per col-pair, 32 slots each.
__global__ __launch_bounds__(256, 4) void k2b_agg(
        const short* __restrict__ ea_s, const int* __restrict__ col_s,
        const int* __restrict__ row_s,
        const short* __restrict__ pW, const float* __restrict__ bf1v,
        const float* __restrict__ bf2v,
        const short* __restrict__ h, float* __restrict__ agg) {
    __shared__ char t1S[64 * 512];   // t1 p-order -> h rows -> msg tile (in place)
    __shared__ int colS[64], rowS[64];
    int s0 = blockIdx.x * 64;
    int tid = threadIdx.x;
    int lane = tid & 63, w = tid >> 6;
    int q = lane >> 4, l15 = lane & 15;

    if (tid < 64) {
        colS[tid] = col_s[s0 + tid];
        rowS[tid] = row_s[s0 + tid];
    }

    f32x4 acc[4][4];
    #pragma unroll
    for (int mf = 0; mf < 4; ++mf)
        #pragma unroll
        for (int nf = 0; nf < 4; ++nf) acc[mf][nf] = f32x4{0.f, 0.f, 0.f, 0.f};

    // phase 1: t1 = ssp(ea_s @ Wf1 + b1), K=64, M=64; A direct from global bf16
    #pragma unroll
    for (int ks = 0; ks < 2; ++ks) {
        bf16x8 a[4];
        #pragma unroll
        for (int mf = 0; mf < 4; ++mf)
            a[mf] = *(const bf16x8*)(ea_s + (size_t)(s0 + mf * 16 + l15) * ECH + ks * 32 + q * 8);
        #pragma unroll
        for (int nf = 0; nf < 4; ++nf) {
            bf16x8 b = *(const bf16x8*)(pW + PO_WF1 + (((ks * 16 + w * 4 + nf) * 64) + lane) * 8);
            #pragma unroll
            for (int mf = 0; mf < 4; ++mf)
                acc[mf][nf] = __builtin_amdgcn_mfma_f32_16x16x32_bf16(a[mf], b, acc[mf][nf], 0, 0, 0);
        }
    }
    // ssp + bias, write t1 in p-order: b64 per (mf,r)
    {
        float bia[4];
        #pragma unroll
        for (int nf = 0; nf < 4; ++nf) bia[nf] = bf1v[w * 64 + nf * 16 + l15];
        #pragma unroll
        for (int mf = 0; mf < 4; ++mf) {
            #pragma unroll
            for (int r = 0; r < 4; ++r) {
                int row = mf * 16 + q * 4 + r;
                u32x2 v = {cvtpk(sspf(acc[mf][0][r] + bia[0]), sspf(acc[mf][1][r] + bia[1])),
                           cvtpk(sspf(acc[mf][2][r] + bia[2]), sspf(acc[mf][3][r] + bia[3]))};
                *(u32x2*)(t1S + row * 512 + ((w * 128 + l15 * 8) ^ ((row & 7) << 4))) = v;
            }
        }
    }
    __syncthreads();

    #pragma unroll
    for (int mf = 0; mf < 4; ++mf)
        #pragma unroll
        for (int nf = 0; nf < 4; ++nf) acc[mf][nf] = f32x4{0.f, 0.f, 0.f, 0.f};

    // phase 2: Wf = t1 @ Wf2 + b2, K=256, M=64 (k in p-order)
    for (int ks = 0; ks < 8; ++ks) {
        bf16x8 a[4];
        #pragma unroll
        for (int mf = 0; mf < 4; ++mf) {
            int row = mf * 16 + l15;
            a[mf] = *(const bf16x8*)(t1S + row * 512 + ((ks * 64 + q * 16) ^ ((row & 7) << 4)));
        }
        #pragma unroll
        for (int nf = 0; nf < 4; ++nf) {
            bf16x8 b = *(const bf16x8*)(pW + PO_WF2 + (((ks * 16 + w * 4 + nf) * 64) + lane) * 8);
            #pragma unroll
            for (int mf = 0; mf < 4; ++mf)
                acc[mf][nf] = __builtin_amdgcn_mfma_f32_16x16x32_bf16(a[mf], b, acc[mf][nf], 0, 0, 0);
        }
    }
    __syncthreads();   // t1S reads done; reuse region for h rows

    {   // stage h[colS[0..63]] (p-order rows) into LDS: 4 thr/row, 8x16B each
        int r = tid >> 2, ch = tid & 3;
        const short* hp = h + (size_t)colS[r] * NFF;
        int sw = (r & 7) << 4;
        #pragma unroll
        for (int i = 0; i < 8; ++i) {
            int chunk = ch + i * 4;
            bf16x8 v = *(const bf16x8*)(hp + chunk * 8);
            *(bf16x8*)(t1S + r * 512 + ((chunk * 16) ^ sw)) = v;
        }
    }
    __syncthreads();

    // in-place modulate: t1S[eloc][p-pair] = h * Wf  (each addr owned by one thread)
    {
        float bia[4];
        #pragma unroll
        for (int nf = 0; nf < 4; ++nf) bia[nf] = bf2v[w * 64 + nf * 16 + l15];
        #pragma unroll
        for (int mf = 0; mf < 4; ++mf) {
            #pragma unroll
            for (int r = 0; r < 4; ++r) {
                int eloc = mf * 16 + q * 4 + r;
                char* addr = t1S + eloc * 512 + ((w * 128 + l15 * 8) ^ ((eloc & 7) << 4));
                u32x2 hv = *(const u32x2*)addr;
                float m0 = bfu_lo(hv[0]) * (acc[mf][0][r] + bia[0]);
                float m1 = bfu_hi(hv[0]) * (acc[mf][1][r] + bia[1]);
                float m2 = bfu_lo(hv[1]) * (acc[mf][2][r] + bia[2]);
                float m3 = bfu_hi(hv[1]) * (acc[mf][3][r] + bia[3]);
                u32x2 out = {cvtpk(m0, m1), cvtpk(m2, m3)};
                *(u32x2*)addr = out;
            }
        }
    }
    __syncthreads();

    // segment-reduce: ALL 256 threads. thread = (half, cp): cp = tid&127 owns
    // cols (2cp, 2cp+1) in p-order; half = tid>>7 walks slots [half*32, half*32+32).
    {
        int cp = tid & 127;
        int h0 = (tid >> 7) * 32;
        float a0 = 0.f, a1 = 0.f;
        int cur = rowS[h0];
        bool first = true;
        for (int e = h0; e < h0 + 32; ++e) {
            int rw = rowS[e];
            if (rw != cur) {
                float* dst = agg + (size_t)cur * NFF + cp * 2;
                if (first) { atomicAdd(dst, a0); atomicAdd(dst + 1, a1); first = false; }
                else       { dst[0] = a0; dst[1] = a1; }
                a0 = 0.f; a1 = 0.f;
                cur = rw;
            }
            unsigned v = *(const unsigned*)(t1S + e * 512 + ((cp * 4) ^ ((e & 7) << 4)));
            a0 += bfu_lo(v);
            a1 += bfu_hi(v);
        }
        float* dst = agg + (size_t)cur * NFF + cp * 2;
        atomicAdd(dst, a0); atomicAdd(dst + 1, a1);
    }
}

// ---- K3: load agg (fp32, p-order) + MFMA node GEMMs ----
__global__ __launch_bounds__(256) void k3_node(
        const float* __restrict__ agg,
        const short* __restrict__ pW, const float* __restrict__ bl2,
        const float* __restrict__ bl3,
        const float* __restrict__ x, float* __restrict__ xo) {
    __shared__ char aggS[32 * 512];  // [32][256] bf16 p-order, swizzled
    __shared__ char t2S[32 * 256];   // [32][128] bf16 p2-order, swizzled
    int n0 = blockIdx.x * 32;
    int tid = threadIdx.x;
    int lane = tid & 63, w = tid >> 6, q = lane >> 4, l15 = lane & 15;

    {   // coalesced agg load: 8 thr/node, 32 cols each
        int nd = tid >> 3, c0 = (tid & 7) * 32;
        int n = n0 + nd;
        float a[32];
        if (n < NN) {
            const float4* src = (const float4*)(agg + (size_t)n * NFF + c0);
            #pragma unroll
            for (int j = 0; j < 8; ++j) {
                float4 v = src[j];
                a[4 * j] = v.x; a[4 * j + 1] = v.y; a[4 * j + 2] = v.z; a[4 * j + 3] = v.w;
            }
        } else {
            #pragma unroll
            for (int i = 0; i < 32; ++i) a[i] = 0.f;
        }
        int sw = (nd & 7) << 4;
        #pragma unroll
        for (int j = 0; j < 4; ++j) {
            u32x4 v = {cvtpk(a[j * 8 + 0], a[j * 8 + 1]), cvtpk(a[j * 8 + 2], a[j * 8 + 3]),
                       cvtpk(a[j * 8 + 4], a[j * 8 + 5]), cvtpk(a[j * 8 + 6], a[j * 8 + 7])};
            *(u32x4*)(aggS + nd * 512 + (((c0 + j * 8) * 2) ^ sw)) = v;
        }
    }
    __syncthreads();

    // GEMM1: t2 = ssp(agg @ Wl2 + b2), k in p-order (pWl2 matches)
    f32x4 acc[2][2];
    #pragma unroll
    for (int mf = 0; mf < 2; ++mf)
        #pragma unroll
        for (int nf = 0; nf < 2; ++nf) acc[mf][nf] = f32x4{0.f, 0.f, 0.f, 0.f};
    for (int ks = 0; ks < 8; ++ks) {
        bf16x8 a[2];
        #pragma unroll
        for (int mf = 0; mf < 2; ++mf) {
            int row = mf * 16 + l15;
            a[mf] = *(const bf16x8*)(aggS + row * 512 + ((ks * 64 + q * 16) ^ ((row & 7) << 4)));
        }
        #pragma unroll
        for (int nf = 0; nf < 2; ++nf) {
            bf16x8 b = *(const bf16x8*)(pW + PO_WL2 + (((ks * 8 + w * 2 + nf) * 64) + lane) * 8);
            #pragma unroll
            for (int mf = 0; mf < 2; ++mf)
                acc[mf][nf] = __builtin_amdgcn_mfma_f32_16x16x32_bf16(a[mf], b, acc[mf][nf], 0, 0, 0);
        }
    }
    {   // t2 in p2-order: b32 per (mf,r)
        float bia[2];
        #pragma unroll
        for (int nf = 0; nf < 2; ++nf) bia[nf] = bl2[w * 32 + nf * 16 + l15];
        #pragma unroll
        for (int mf = 0; mf < 2; ++mf) {
            #pragma unroll
            for (int r = 0; r < 4; ++r) {
                int row = mf * 16 + q * 4 + r;
                unsigned u = cvtpk(sspf(acc[mf][0][r] + bia[0]), sspf(acc[mf][1][r] + bia[1]));
                *(unsigned*)(t2S + row * 256 + ((w * 64 + l15 * 4) ^ ((row & 7) << 4))) = u;
            }
        }
    }
    __syncthreads();

    // GEMM2: y = t2 @ Wl3 + b3, k in p2-order (pWl3 matches)
    f32x4 acc2[2][2];
    #pragma unroll
    for (int mf = 0; mf < 2; ++mf)
        #pragma unroll
        for (int nf = 0; nf < 2; ++nf) acc2[mf][nf] = f32x4{0.f, 0.f, 0.f, 0.f};
    #pragma unroll
    for (int ks = 0; ks < 4; ++ks) {
        bf16x8 a[2];
        #pragma unroll
        for (int mf = 0; mf < 2; ++mf) {
            int row = mf * 16 + l15;
            a[mf] = *(const bf16x8*)(t2S + row * 256 + ((ks * 64 + q * 16) ^ ((row & 7) << 4)));
        }
        #pragma unroll
        for (int nf = 0; nf < 2; ++nf) {
            bf16x8 b = *(const bf16x8*)(pW + PO_WL3 + (((ks * 8 + w * 2 + nf) * 64) + lane) * 8);
            #pragma unroll
            for (int mf = 0; mf < 2; ++mf)
                acc2[mf][nf] = __builtin_amdgcn_mfma_f32_16x16x32_bf16(a[mf], b, acc2[mf][nf], 0, 0, 0);
        }
    }
    #pragma unroll
    for (int nf = 0; nf < 2; ++nf) {
        int col = w * 32 + nf * 16 + l15;
        float bias = bl3[col];
        #pragma unroll
        for (int mf = 0; mf < 2; ++mf) {
            #pragma unroll
            for (int r = 0; r < 4; ++r) {
                int n = n0 + mf * 16 + q * 4 + r;
                if (n < NN) {
                    size_t o = (size_t)n * CC + col;
                    xo[o] = fmaxf(acc2[mf][nf][r] + bias, 0.f) + x[o];
                }
            }
        }
    }
}

// ---- K4: MFMA e_out = tanh([ea | xo[row]+xo[col]] @ We + be), SORTED order ----
// Processes sorted slots (row-ascending): xo[row] gathers get L1/L2 locality.
// ea gathered fp32 via perm; eo stored scattered at eo[perm_s[slot]] (full 64B segs).
__global__ __launch_bounds__(256) void k4_mfma(
        const float* __restrict__ ea, const int* __restrict__ perm_s,
        const int* __restrict__ col_s, const int* __restrict__ row_s,
        const float* __restrict__ xo, const short* __restrict__ pW,
        const float* __restrict__ bev, float* __restrict__ eo) {
    __shared__ char aS[64 * 256];    // [64][128] bf16 (xo-sum part), swizzled
    __shared__ int eoS[64];
    int s0 = blockIdx.x * 64;
    int tid = threadIdx.x;
    int lane = tid & 63, w = tid >> 6;
    int q = lane >> 4, l15 = lane & 15;

    if (tid < 64) eoS[tid] = perm_s[s0 + tid];

    {   // stage xo[row]+xo[col] (k 64..191) for sorted slots
        int e = tid >> 2, p = tid & 3;
        int rr = row_s[s0 + e], cc = col_s[s0 + e];
        const float4* xr = (const float4*)(xo + (size_t)rr * CC);
        const float4* xc = (const float4*)(xo + (size_t)cc * CC);
        int sw = (e & 7) << 4;
        #pragma unroll
        for (int it = 0; it < 8; ++it) {
            int fi = p + it * 4;
            float4 va = xr[fi], vb = xc[fi];
            u32x2 hv = {cvtpk(va.x + vb.x, va.y + vb.y), cvtpk(va.z + vb.z, va.w + vb.w)};
            *(u32x2*)(aS + e * 256 + ((fi * 8) ^ sw)) = hv;
        }
    }
    __syncthreads();

    f32x4 acc[8];
    #pragma unroll
    for (int nf = 0; nf < 8; ++nf) acc[nf] = f32x4{0.f, 0.f, 0.f, 0.f};

    int row = w * 16 + l15;
    int eorig = eoS[row];
    // ks 0..1: A gathered from ea[eorig] (fp32 -> bf16 in regs)
    #pragma unroll
    for (int ks = 0; ks < 2; ++ks) {
        const float4* src = (const float4*)(ea + (size_t)eorig * ECH + ks * 32 + q * 8);
        float4 f0 = src[0], f1 = src[1];
        cvu cv;
        cv.u = u32x4{cvtpk(f0.x, f0.y), cvtpk(f0.z, f0.w),
                     cvtpk(f1.x, f1.y), cvtpk(f1.z, f1.w)};
        bf16x8 a = cv.b;
        #pragma unroll
        for (int nf = 0; nf < 8; ++nf) {
            bf16x8 b = *(const bf16x8*)(pW + PO_WE + (((ks * 8 + nf) * 64) + lane) * 8);
            acc[nf] = __builtin_amdgcn_mfma_f32_16x16x32_bf16(a, b, acc[nf], 0, 0, 0);
        }
    }
    // ks 2..5: A from LDS (xo-sum part; local k index 0..127)
    #pragma unroll
    for (int ks = 2; ks < 6; ++ks) {
        bf16x8 a = *(const bf16x8*)(aS + row * 256 + (((ks - 2) * 64 + q * 16) ^ ((row & 7) << 4)));
        #pragma unroll
        for (int nf = 0; nf < 8; ++nf) {
            bf16x8 b = *(const bf16x8*)(pW + PO_WE + (((ks * 8 + nf) * 64) + lane) * 8);
            acc[nf] = __builtin_amdgcn_mfma_f32_16x16x32_bf16(a, b, acc[nf], 0, 0, 0);
        }
    }
    #pragma unroll
    for (int nf = 0; nf < 8; ++nf) {
        int col = nf * 16 + l15;
        float bias = bev[col];
        #pragma unroll
        for (int r = 0; r < 4; ++r) {
            int e = eoS[w * 16 + q * 4 + r];
            eo[(size_t)e * CC + col] = ftanh(acc[nf][r] + bias);
        }
    }
}

extern "C" void kernel_launch(void* const* d_in, const int* in_sizes, int n_in,
                              void* d_out, int out_size, void* d_ws, size_t ws_size,
                              hipStream_t stream) {
    const float* x   = (const float*)d_in[0];
    const int*   ei  = (const int*)d_in[1];
    const float* ea  = (const float*)d_in[2];
    const float* Wf1 = (const float*)d_in[4];
    const float* bf1 = (const float*)d_in[5];
    const float* Wf2 = (const float*)d_in[6];
    const float* bf2 = (const float*)d_in[7];
    const float* Wl1 = (const float*)d_in[8];
    const float* Wl2 = (const float*)d_in[9];
    const float* bl2 = (const float*)d_in[10];
    const float* Wl3 = (const float*)d_in[11];
    const float* bl3 = (const float*)d_in[12];
    const float* We  = (const float*)d_in[13];
    const float* be  = (const float*)d_in[14];

    float* xo = (float*)d_out;                 // [N, C] final
    float* eo = xo + (size_t)NN * CC;          // [E, C] final

    // region reuse (sequential lifetimes, fully rewritten each call):
    //   h    bf16 [N,256] p-order in the xo region (dead before k3 writes xo)
    //   ea_s / agg in the TAIL of the eo region (dead before k4 writes eo)
    //   perm_s/col_s/row_s in ws (read by k4 WHILE it writes eo -> must not alias eo)
    short* h    = (short*)xo;                                  // 25.6 MB
    char*  top  = (char*)d_out + (size_t)out_size * sizeof(float);
    short* ea_s = (short*)(top - (size_t)NE * ECH * 2);        // 76.8 MB
    float* agg  = (float*)((char*)ea_s - (size_t)NN * NFF * 4); // 51.2 MB

    // ws: [packed weights][cnt][offw][bsum][perm_s E][col_s E][row_s E]  ~8 MB
    short* pW     = (short*)d_ws;
    int* cnt      = (int*)((char*)d_ws + 393216);
    int* offw     = cnt + NN;
    int* bsum     = offw + NN;
    int* perm_s   = bsum + 256;
    int* col_s    = perm_s + NE;
    int* row_s    = col_s + NE;

    const int NB = (NN + 255) / 256;

    kpack<<<P_TOT / 256, 256, 0, stream>>>(Wf1, Wf2, We, Wl1, Wl2, Wl3, pW);
    k0_zero2<<<1024, 256, 0, stream>>>(agg, (long)NN * NFF / 4, (float*)cnt, NN / 4);
    k_cnt<<<(NE + 255) / 256, 256, 0, stream>>>(ei, cnt);
    k_scan1<<<NB, 256, 0, stream>>>(cnt, offw, bsum);
    k_scan2<<<1, 256, 0, stream>>>(bsum, NB);
    k_scan3<<<NB, 256, 0, stream>>>(offw, bsum);
    k_scatter<<<(NE + 255) / 256, 256, 0, stream>>>(ei, ea, offw, ea_s, col_s, row_s, perm_s);
    k1_h<<<(NN + 31) / 32, 256, 0, stream>>>(x, pW, h);
    k2b_agg<<<NE / 64, 256, 0, stream>>>(ea_s, col_s, row_s, pW, bf1, bf2, h, agg);
    k3_node<<<(NN + 31) / 32, 256, 0, stream>>>(agg, pW, bl2, bl3, x, xo);
    k4_mfma<<<NE / 64, 256, 0, stream>>>(ea, perm_s, col_s, row_s, xo, pW, be, eo);
}

// Round 17
// 525.067 us; speedup vs baseline: 1.0580x; 1.0312x over previous
//
#include <hip/hip_runtime.h>

#define NN  50000
#define NE  600000
#define CC  128
#define NFF 256
#define ECH 64
#define EIN 192   // ECH + CC

typedef __attribute__((ext_vector_type(8))) short bf16x8;
typedef __attribute__((ext_vector_type(4))) float f32x4;
typedef __attribute__((ext_vector_type(4))) unsigned u32x4;
typedef __attribute__((ext_vector_type(2))) unsigned u32x2;

// fast shifted-softplus: softplus(v)-ln2 via hw exp/log
__device__ __forceinline__ float sspf(float v) {
    float e = __expf(-fabsf(v));
    return fmaxf(v, 0.f) + __logf(1.f + e) - 0.693147180559945f;
}
// fast tanh via hw exp
__device__ __forceinline__ float ftanh(float v) {
    float e = __expf(-2.f * fabsf(v));
    float r = (1.f - e) / (1.f + e);
    return copysignf(r, v);
}
__device__ __forceinline__ short bf16r(float f) {
    unsigned u = __float_as_uint(f);
    u = (u + 0x7FFFu + ((u >> 16) & 1u)) >> 16;
    return (short)u;
}
// packed fp32x2 -> bf16x2 (RNE), single VALU op
__device__ __forceinline__ unsigned cvtpk(float lo, float hi) {
    unsigned r;
    asm("v_cvt_pk_bf16_f32 %0, %1, %2" : "=v"(r) : "v"(lo), "v"(hi));
    return r;
}
__device__ __forceinline__ float bfu_lo(unsigned u) { return __uint_as_float(u << 16); }
__device__ __forceinline__ float bfu_hi(unsigned u) { return __uint_as_float(u & 0xffff0000u); }

// ---- pack ALL weights to bf16 fragment-linear layout for mfma_16x16x32 B-op.
// 256-col tensors (h, t1, agg) live in fragment order p = w*64 + l15*4 + nf;
// consumers' k-dims packed with orig_k(p) = (p>>6)*64+(p&3)*16+((p>>2)&15).
// 128-col t2 (k3-internal): p2 order, orig_k2(p) = (p>>5)*32+(p&1)*16+((p&31)>>1).
#define PO_WF1 0
#define PO_WF2 16384
#define PO_WE  81920
#define PO_WL1 106496
#define PO_WL2 139264
#define PO_WL3 172032
#define P_TOT  188416
__global__ void kpack(const float* __restrict__ Wf1, const float* __restrict__ Wf2,
                      const float* __restrict__ We,  const float* __restrict__ Wl1,
                      const float* __restrict__ Wl2, const float* __restrict__ Wl3,
                      short* __restrict__ p) {
    int i = blockIdx.x * 256 + threadIdx.x;
    if (i < PO_WF2) {                      // Wf1 [64][256]: k orig, n orig
        int t = i - PO_WF1;
        int j = t & 7, lane = (t >> 3) & 63, n16 = (t >> 9) & 15, ks = t >> 13;
        p[i] = bf16r(Wf1[(ks * 32 + (lane >> 4) * 8 + j) * NFF + n16 * 16 + (lane & 15)]);
    } else if (i < PO_WE) {                // Wf2 [256][256]: k in t1 p-order
        int t = i - PO_WF2;
        int j = t & 7, lane = (t >> 3) & 63, n16 = (t >> 9) & 15, ks = t >> 13;
        int kp = ks * 32 + (lane >> 4) * 8 + j;
        int k = (kp >> 6) * 64 + (kp & 3) * 16 + ((kp >> 2) & 15);
        p[i] = bf16r(Wf2[k * NFF + n16 * 16 + (lane & 15)]);
    } else if (i < PO_WL1) {               // We [192][128]: k orig, n orig
        int t = i - PO_WE;
        int j = t & 7, lane = (t >> 3) & 63, n16 = (t >> 9) & 7, ks = t >> 12;
        p[i] = bf16r(We[(ks * 32 + (lane >> 4) * 8 + j) * CC + n16 * 16 + (lane & 15)]);
    } else if (i < PO_WL2) {               // Wl1 [128][256]: k orig, n orig
        int t = i - PO_WL1;
        int j = t & 7, lane = (t >> 3) & 63, n16 = (t >> 9) & 15, ks = t >> 13;
        p[i] = bf16r(Wl1[(ks * 32 + (lane >> 4) * 8 + j) * NFF + n16 * 16 + (lane & 15)]);
    } else if (i < PO_WL3) {               // Wl2 [256][128]: k in agg p-order
        int t = i - PO_WL2;
        int j = t & 7, lane = (t >> 3) & 63, n16 = (t >> 9) & 7, ks = t >> 12;
        int kp = ks * 32 + (lane >> 4) * 8 + j;
        int k = (kp >> 6) * 64 + (kp & 3) * 16 + ((kp >> 2) & 15);
        p[i] = bf16r(Wl2[k * CC + n16 * 16 + (lane & 15)]);
    } else if (i < P_TOT) {                // Wl3 [128][128]: k in t2 p2-order
        int t = i - PO_WL3;
        int j = t & 7, lane = (t >> 3) & 63, n16 = (t >> 9) & 7, ks = t >> 12;
        int kp = ks * 32 + (lane >> 4) * 8 + j;
        int k = (kp >> 5) * 32 + (kp & 1) * 16 + ((kp & 31) >> 1);
        p[i] = bf16r(Wl3[k * CC + n16 * 16 + (lane & 15)]);
    }
}

// ---- K0: zero two regions in one launch (grid-stride) ----
__global__ void k0_zero2(float* __restrict__ p0, long n40,
                         float* __restrict__ p1, long n41) {
    long i = (long)blockIdx.x * blockDim.x + threadIdx.x;
    long stride = (long)gridDim.x * blockDim.x;
    float4 z = {0.f, 0.f, 0.f, 0.f};
    for (long k = i; k < n40; k += stride) ((float4*)p0)[k] = z;
    for (long k = i; k < n41; k += stride) ((float4*)p1)[k] = z;
}

// ---- CSR build ----
__global__ void k_cnt(const int* __restrict__ eidx, int* __restrict__ cnt) {
    int e = blockIdx.x * 256 + threadIdx.x;
    if (e < NE) atomicAdd(&cnt[eidx[e]], 1);
}

// 3-phase scan (NB blocks of 256)
__global__ __launch_bounds__(256) void k_scan1(const int* __restrict__ cnt,
                                               int* __restrict__ offw,
                                               int* __restrict__ bsum) {
    __shared__ int sw_[4];
    int i = blockIdx.x * 256 + threadIdx.x;
    int lane = threadIdx.x & 63, wv = threadIdx.x >> 6;
    int v = (i < NN) ? cnt[i] : 0;
    int inc = v;
    #pragma unroll
    for (int d = 1; d < 64; d <<= 1) {
        int t = __shfl_up(inc, d, 64);
        if (lane >= d) inc += t;
    }
    if (lane == 63) sw_[wv] = inc;
    __syncthreads();
    int woff = 0;
    #pragma unroll
    for (int k = 0; k < 4; ++k) woff += (k < wv) ? sw_[k] : 0;
    if (i < NN) offw[i] = woff + inc - v;
    if (threadIdx.x == 255) bsum[blockIdx.x] = woff + inc;
}

__global__ __launch_bounds__(256) void k_scan2(int* __restrict__ bsum, int nb) {
    __shared__ int sw_[4];
    int t = threadIdx.x;
    int lane = t & 63, wv = t >> 6;
    int v = (t < nb) ? bsum[t] : 0;
    int inc = v;
    #pragma unroll
    for (int d = 1; d < 64; d <<= 1) {
        int s = __shfl_up(inc, d, 64);
        if (lane >= d) inc += s;
    }
    if (lane == 63) sw_[wv] = inc;
    __syncthreads();
    int woff = 0;
    #pragma unroll
    for (int k = 0; k < 4; ++k) woff += (k < wv) ? sw_[k] : 0;
    if (t < nb) bsum[t] = woff + inc - v;
}

__global__ void k_scan3(int* __restrict__ offw, const int* __restrict__ bsum) {
    int i = blockIdx.x * 256 + threadIdx.x;
    if (i < NN) offw[i] += bsum[blockIdx.x];
}

// ---- scatter: physically permute edges into row-sorted order (bf16 ea_s) ----
__global__ void k_scatter(const int* __restrict__ eidx, const float* __restrict__ ea,
                          int* __restrict__ offw, short* __restrict__ ea_s,
                          int* __restrict__ col_s, int* __restrict__ row_s) {
    int e = blockIdx.x * 256 + threadIdx.x;
    if (e >= NE) return;
    int r = eidx[e], c = eidx[NE + e];
    int pos = atomicAdd(&offw[r], 1);
    col_s[pos] = c;
    row_s[pos] = r;
    const float4* src = (const float4*)(ea + (size_t)e * ECH);
    short* dst = ea_s + (size_t)pos * ECH;
    #pragma unroll
    for (int i = 0; i < 4; ++i) {
        float4 f0 = src[4 * i], f1 = src[4 * i + 1], f2 = src[4 * i + 2], f3 = src[4 * i + 3];
        u32x4 v0 = {cvtpk(f0.x, f0.y), cvtpk(f0.z, f0.w), cvtpk(f1.x, f1.y), cvtpk(f1.z, f1.w)};
        u32x4 v1 = {cvtpk(f2.x, f2.y), cvtpk(f2.z, f2.w), cvtpk(f3.x, f3.y), cvtpk(f3.z, f3.w)};
        *(u32x4*)(dst + i * 16) = v0;
        *(u32x4*)(dst + i * 16 + 8) = v1;
    }
}

// ---- K1: h[N,256] = x @ Wl1 (MFMA), h stored in p-order ----
__global__ __launch_bounds__(256) void k1_h(const float* __restrict__ x,
                                            const short* __restrict__ pW,
                                            short* __restrict__ h) {
    __shared__ char xS[32 * 256];   // [32][128] bf16, swizzled
    int n0 = blockIdx.x * 32;
    int tid = threadIdx.x;
    int lane = tid & 63, w = tid >> 6, q = lane >> 4, l15 = lane & 15;
    {
        int r = tid >> 3, seg = tid & 7;
        int rr = min(n0 + r, NN - 1);
        const float4* src = (const float4*)(x + (size_t)rr * CC + seg * 16);
        float4 f0 = src[0], f1 = src[1], f2 = src[2], f3 = src[3];
        u32x4 c0 = {cvtpk(f0.x, f0.y), cvtpk(f0.z, f0.w), cvtpk(f1.x, f1.y), cvtpk(f1.z, f1.w)};
        u32x4 c1 = {cvtpk(f2.x, f2.y), cvtpk(f2.z, f2.w), cvtpk(f3.x, f3.y), cvtpk(f3.z, f3.w)};
        int sw = (r & 7) << 4;
        *(u32x4*)(xS + r * 256 + ((seg * 32) ^ sw)) = c0;
        *(u32x4*)(xS + r * 256 + ((seg * 32 + 16) ^ sw)) = c1;
    }
    __syncthreads();

    f32x4 acc[2][4];
    #pragma unroll
    for (int mf = 0; mf < 2; ++mf)
        #pragma unroll
        for (int nf = 0; nf < 4; ++nf) acc[mf][nf] = f32x4{0.f, 0.f, 0.f, 0.f};

    #pragma unroll
    for (int ks = 0; ks < 4; ++ks) {
        bf16x8 a[2];
        #pragma unroll
        for (int mf = 0; mf < 2; ++mf) {
            int row = mf * 16 + l15;
            a[mf] = *(const bf16x8*)(xS + row * 256 + ((ks * 64 + q * 16) ^ ((row & 7) << 4)));
        }
        #pragma unroll
        for (int nf = 0; nf < 4; ++nf) {
            bf16x8 b = *(const bf16x8*)(pW + PO_WL1 + (((ks * 16 + w * 4 + nf) * 64) + lane) * 8);
            #pragma unroll
            for (int mf = 0; mf < 2; ++mf)
                acc[mf][nf] = __builtin_amdgcn_mfma_f32_16x16x32_bf16(a[mf], b, acc[mf][nf], 0, 0, 0);
        }
    }
    #pragma unroll
    for (int mf = 0; mf < 2; ++mf) {
        #pragma unroll
        for (int r = 0; r < 4; ++r) {
            int n = n0 + mf * 16 + q * 4 + r;
            if (n < NN) {
                u32x2 v = {cvtpk(acc[mf][0][r], acc[mf][1][r]),
                           cvtpk(acc[mf][2][r], acc[mf][3][r])};
                *(u32x2*)(h + (size_t)n * NFF + w * 64 + l15 * 4) = v;
            }
        }
    }
}

// ---- K2b: FUSED filter-net + modulate + in-LDS segment-reduce -> agg fp32 ----
// 64 sorted slots/block, 4 waves; wave w owns cols [w*64, w*64+64).
// Walk: ALL 256 threads; 2 threads per col-pair, 32 slots each.
__global__ __launch_bounds__(256, 4) void k2b_agg(
        const short* __restrict__ ea_s, const int* __restrict__ col_s,
        const int* __restrict__ row_s,
        const short* __restrict__ pW, const float* __restrict__ bf1v,
        const float* __restrict__ bf2v,
        const short* __restrict__ h, float* __restrict__ agg) {
    __shared__ char t1S[64 * 512];   // t1 p-order -> h rows -> msg tile (in place)
    __shared__ int colS[64], rowS[64];
    int s0 = blockIdx.x * 64;
    int tid = threadIdx.x;
    int lane = tid & 63, w = tid >> 6;
    int q = lane >> 4, l15 = lane & 15;

    if (tid < 64) {
        colS[tid] = col_s[s0 + tid];
        rowS[tid] = row_s[s0 + tid];
    }

    f32x4 acc[4][4];
    #pragma unroll
    for (int mf = 0; mf < 4; ++mf)
        #pragma unroll
        for (int nf = 0; nf < 4; ++nf) acc[mf][nf] = f32x4{0.f, 0.f, 0.f, 0.f};

    // phase 1: t1 = ssp(ea_s @ Wf1 + b1), K=64, M=64; A direct from global bf16
    #pragma unroll
    for (int ks = 0; ks < 2; ++ks) {
        bf16x8 a[4];
        #pragma unroll
        for (int mf = 0; mf < 4; ++mf)
            a[mf] = *(const bf16x8*)(ea_s + (size_t)(s0 + mf * 16 + l15) * ECH + ks * 32 + q * 8);
        #pragma unroll
        for (int nf = 0; nf < 4; ++nf) {
            bf16x8 b = *(const bf16x8*)(pW + PO_WF1 + (((ks * 16 + w * 4 + nf) * 64) + lane) * 8);
            #pragma unroll
            for (int mf = 0; mf < 4; ++mf)
                acc[mf][nf] = __builtin_amdgcn_mfma_f32_16x16x32_bf16(a[mf], b, acc[mf][nf], 0, 0, 0);
        }
    }
    // ssp + bias, write t1 in p-order: b64 per (mf,r)
    {
        float bia[4];
        #pragma unroll
        for (int nf = 0; nf < 4; ++nf) bia[nf] = bf1v[w * 64 + nf * 16 + l15];
        #pragma unroll
        for (int mf = 0; mf < 4; ++mf) {
            #pragma unroll
            for (int r = 0; r < 4; ++r) {
                int row = mf * 16 + q * 4 + r;
                u32x2 v = {cvtpk(sspf(acc[mf][0][r] + bia[0]), sspf(acc[mf][1][r] + bia[1])),
                           cvtpk(sspf(acc[mf][2][r] + bia[2]), sspf(acc[mf][3][r] + bia[3]))};
                *(u32x2*)(t1S + row * 512 + ((w * 128 + l15 * 8) ^ ((row & 7) << 4))) = v;
            }
        }
    }
    __syncthreads();

    #pragma unroll
    for (int mf = 0; mf < 4; ++mf)
        #pragma unroll
        for (int nf = 0; nf < 4; ++nf) acc[mf][nf] = f32x4{0.f, 0.f, 0.f, 0.f};

    // phase 2: Wf = t1 @ Wf2 + b2, K=256, M=64 (k in p-order)
    for (int ks = 0; ks < 8; ++ks) {
        bf16x8 a[4];
        #pragma unroll
        for (int mf = 0; mf < 4; ++mf) {
            int row = mf * 16 + l15;
            a[mf] = *(const bf16x8*)(t1S + row * 512 + ((ks * 64 + q * 16) ^ ((row & 7) << 4)));
        }
        #pragma unroll
        for (int nf = 0; nf < 4; ++nf) {
            bf16x8 b = *(const bf16x8*)(pW + PO_WF2 + (((ks * 16 + w * 4 + nf) * 64) + lane) * 8);
            #pragma unroll
            for (int mf = 0; mf < 4; ++mf)
                acc[mf][nf] = __builtin_amdgcn_mfma_f32_16x16x32_bf16(a[mf], b, acc[mf][nf], 0, 0, 0);
        }
    }
    __syncthreads();   // t1S reads done; reuse region for h rows

    {   // stage h[colS[0..63]] (p-order rows) into LDS: 4 thr/row, 8x16B each
        int r = tid >> 2, ch = tid & 3;
        const short* hp = h + (size_t)colS[r] * NFF;
        int sw = (r & 7) << 4;
        #pragma unroll
        for (int i = 0; i < 8; ++i) {
            int chunk = ch + i * 4;
            bf16x8 v = *(const bf16x8*)(hp + chunk * 8);
            *(bf16x8*)(t1S + r * 512 + ((chunk * 16) ^ sw)) = v;
        }
    }
    __syncthreads();

    // in-place modulate: t1S[eloc][p-pair] = h * Wf  (each addr owned by one thread)
    {
        float bia[4];
        #pragma unroll
        for (int nf = 0; nf < 4; ++nf) bia[nf] = bf2v[w * 64 + nf * 16 + l15];
        #pragma unroll
        for (int mf = 0; mf < 4; ++mf) {
            #pragma unroll
            for (int r = 0; r < 4; ++r) {
                int eloc = mf * 16 + q * 4 + r;
                char* addr = t1S + eloc * 512 + ((w * 128 + l15 * 8) ^ ((eloc & 7) << 4));
                u32x2 hv = *(const u32x2*)addr;
                float m0 = bfu_lo(hv[0]) * (acc[mf][0][r] + bia[0]);
                float m1 = bfu_hi(hv[0]) * (acc[mf][1][r] + bia[1]);
                float m2 = bfu_lo(hv[1]) * (acc[mf][2][r] + bia[2]);
                float m3 = bfu_hi(hv[1]) * (acc[mf][3][r] + bia[3]);
                u32x2 out = {cvtpk(m0, m1), cvtpk(m2, m3)};
                *(u32x2*)addr = out;
            }
        }
    }
    __syncthreads();

    // segment-reduce: ALL 256 threads. thread = (half, cp): cp = tid&127 owns
    // cols (2cp, 2cp+1) in p-order; half = tid>>7 walks slots [half*32, half*32+32).
    {
        int cp = tid & 127;
        int h0 = (tid >> 7) * 32;
        float a0 = 0.f, a1 = 0.f;
        int cur = rowS[h0];
        bool first = true;
        for (int e = h0; e < h0 + 32; ++e) {
            int rw = rowS[e];
            if (rw != cur) {
                float* dst = agg + (size_t)cur * NFF + cp * 2;
                if (first) { atomicAdd(dst, a0); atomicAdd(dst + 1, a1); first = false; }
                else       { dst[0] = a0; dst[1] = a1; }
                a0 = 0.f; a1 = 0.f;
                cur = rw;
            }
            unsigned v = *(const unsigned*)(t1S + e * 512 + ((cp * 4) ^ ((e & 7) << 4)));
            a0 += bfu_lo(v);
            a1 += bfu_hi(v);
        }
        float* dst = agg + (size_t)cur * NFF + cp * 2;
        atomicAdd(dst, a0); atomicAdd(dst + 1, a1);
    }
}

// ---- K3: load agg (fp32, p-order) + MFMA node GEMMs ----
__global__ __launch_bounds__(256) void k3_node(
        const float* __restrict__ agg,
        const short* __restrict__ pW, const float* __restrict__ bl2,
        const float* __restrict__ bl3,
        const float* __restrict__ x, float* __restrict__ xo) {
    __shared__ char aggS[32 * 512];  // [32][256] bf16 p-order, swizzled
    __shared__ char t2S[32 * 256];   // [32][128] bf16 p2-order, swizzled
    int n0 = blockIdx.x * 32;
    int tid = threadIdx.x;
    int lane = tid & 63, w = tid >> 6, q = lane >> 4, l15 = lane & 15;

    {   // coalesced agg load: 8 thr/node, 32 cols each
        int nd = tid >> 3, c0 = (tid & 7) * 32;
        int n = n0 + nd;
        float a[32];
        if (n < NN) {
            const float4* src = (const float4*)(agg + (size_t)n * NFF + c0);
            #pragma unroll
            for (int j = 0; j < 8; ++j) {
                float4 v = src[j];
                a[4 * j] = v.x; a[4 * j + 1] = v.y; a[4 * j + 2] = v.z; a[4 * j + 3] = v.w;
            }
        } else {
            #pragma unroll
            for (int i = 0; i < 32; ++i) a[i] = 0.f;
        }
        int sw = (nd & 7) << 4;
        #pragma unroll
        for (int j = 0; j < 4; ++j) {
            u32x4 v = {cvtpk(a[j * 8 + 0], a[j * 8 + 1]), cvtpk(a[j * 8 + 2], a[j * 8 + 3]),
                       cvtpk(a[j * 8 + 4], a[j * 8 + 5]), cvtpk(a[j * 8 + 6], a[j * 8 + 7])};
            *(u32x4*)(aggS + nd * 512 + (((c0 + j * 8) * 2) ^ sw)) = v;
        }
    }
    __syncthreads();

    // GEMM1: t2 = ssp(agg @ Wl2 + b2), k in p-order (pWl2 matches)
    f32x4 acc[2][2];
    #pragma unroll
    for (int mf = 0; mf < 2; ++mf)
        #pragma unroll
        for (int nf = 0; nf < 2; ++nf) acc[mf][nf] = f32x4{0.f, 0.f, 0.f, 0.f};
    for (int ks = 0; ks < 8; ++ks) {
        bf16x8 a[2];
        #pragma unroll
        for (int mf = 0; mf < 2; ++mf) {
            int row = mf * 16 + l15;
            a[mf] = *(const bf16x8*)(aggS + row * 512 + ((ks * 64 + q * 16) ^ ((row & 7) << 4)));
        }
        #pragma unroll
        for (int nf = 0; nf < 2; ++nf) {
            bf16x8 b = *(const bf16x8*)(pW + PO_WL2 + (((ks * 8 + w * 2 + nf) * 64) + lane) * 8);
            #pragma unroll
            for (int mf = 0; mf < 2; ++mf)
                acc[mf][nf] = __builtin_amdgcn_mfma_f32_16x16x32_bf16(a[mf], b, acc[mf][nf], 0, 0, 0);
        }
    }
    {   // t2 in p2-order: b32 per (mf,r)
        float bia[2];
        #pragma unroll
        for (int nf = 0; nf < 2; ++nf) bia[nf] = bl2[w * 32 + nf * 16 + l15];
        #pragma unroll
        for (int mf = 0; mf < 2; ++mf) {
            #pragma unroll
            for (int r = 0; r < 4; ++r) {
                int row = mf * 16 + q * 4 + r;
                unsigned u = cvtpk(sspf(acc[mf][0][r] + bia[0]), sspf(acc[mf][1][r] + bia[1]));
                *(unsigned*)(t2S + row * 256 + ((w * 64 + l15 * 4) ^ ((row & 7) << 4))) = u;
            }
        }
    }
    __syncthreads();

    // GEMM2: y = t2 @ Wl3 + b3, k in p2-order (pWl3 matches)
    f32x4 acc2[2][2];
    #pragma unroll
    for (int mf = 0; mf < 2; ++mf)
        #pragma unroll
        for (int nf = 0; nf < 2; ++nf) acc2[mf][nf] = f32x4{0.f, 0.f, 0.f, 0.f};
    #pragma unroll
    for (int ks = 0; ks < 4; ++ks) {
        bf16x8 a[2];
        #pragma unroll
        for (int mf = 0; mf < 2; ++mf) {
            int row = mf * 16 + l15;
            a[mf] = *(const bf16x8*)(t2S + row * 256 + ((ks * 64 + q * 16) ^ ((row & 7) << 4)));
        }
        #pragma unroll
        for (int nf = 0; nf < 2; ++nf) {
            bf16x8 b = *(const bf16x8*)(pW + PO_WL3 + (((ks * 8 + w * 2 + nf) * 64) + lane) * 8);
            #pragma unroll
            for (int mf = 0; mf < 2; ++mf)
                acc2[mf][nf] = __builtin_amdgcn_mfma_f32_16x16x32_bf16(a[mf], b, acc2[mf][nf], 0, 0, 0);
        }
    }
    #pragma unroll
    for (int nf = 0; nf < 2; ++nf) {
        int col = w * 32 + nf * 16 + l15;
        float bias = bl3[col];
        #pragma unroll
        for (int mf = 0; mf < 2; ++mf) {
            #pragma unroll
            for (int r = 0; r < 4; ++r) {
                int n = n0 + mf * 16 + q * 4 + r;
                if (n < NN) {
                    size_t o = (size_t)n * CC + col;
                    xo[o] = fmaxf(acc2[mf][nf][r] + bias, 0.f) + x[o];
                }
            }
        }
    }
}

// ---- K4: MFMA e_out = tanh([ea | xo[row]+xo[col]] @ We + be) ----
// (round-11 best-known variant: full-LDS A staging, contiguous ea in / eo out)
__global__ __launch_bounds__(256) void k4_mfma(
        const float* __restrict__ ea, const int* __restrict__ eidx,
        const float* __restrict__ xo, const short* __restrict__ pW,
        const float* __restrict__ bev, float* __restrict__ eo) {
    __shared__ char aS[64 * 384];    // [64][192] bf16, swizzled
    int e0 = blockIdx.x * 64;
    int tid = threadIdx.x;
    int lane = tid & 63, w = tid >> 6;
    int q = lane >> 4, l15 = lane & 15;

    {   // stage ea (k 0..63)
        int r = tid >> 2, cp = tid & 3;
        const float4* src = (const float4*)(ea + (size_t)(e0 + r) * ECH + cp * 16);
        float4 f0 = src[0], f1 = src[1], f2 = src[2], f3 = src[3];
        u32x4 c0 = {cvtpk(f0.x, f0.y), cvtpk(f0.z, f0.w), cvtpk(f1.x, f1.y), cvtpk(f1.z, f1.w)};
        u32x4 c1 = {cvtpk(f2.x, f2.y), cvtpk(f2.z, f2.w), cvtpk(f3.x, f3.y), cvtpk(f3.z, f3.w)};
        int sw = (r & 7) << 4;
        *(u32x4*)(aS + r * 384 + ((cp * 32) ^ sw)) = c0;
        *(u32x4*)(aS + r * 384 + ((cp * 32 + 16) ^ sw)) = c1;
    }
    {   // stage xo[row]+xo[col] (k 64..191)
        int e = tid >> 2, p = tid & 3;
        int rr = eidx[e0 + e], cc = eidx[NE + e0 + e];
        const float4* xr = (const float4*)(xo + (size_t)rr * CC);
        const float4* xc = (const float4*)(xo + (size_t)cc * CC);
        int sw = (e & 7) << 4;
        #pragma unroll
        for (int it = 0; it < 8; ++it) {
            int fi = p + it * 4;
            float4 va = xr[fi], vb = xc[fi];
            u32x2 hv = {cvtpk(va.x + vb.x, va.y + vb.y), cvtpk(va.z + vb.z, va.w + vb.w)};
            int byte = (ECH + fi * 4) * 2;
            *(u32x2*)(aS + e * 384 + (byte ^ sw)) = hv;
        }
    }
    __syncthreads();

    f32x4 acc[8];
    #pragma unroll
    for (int nf = 0; nf < 8; ++nf) acc[nf] = f32x4{0.f, 0.f, 0.f, 0.f};

    #pragma unroll
    for (int ks = 0; ks < 6; ++ks) {
        int row = w * 16 + l15;
        bf16x8 a = *(const bf16x8*)(aS + row * 384 + ((ks * 64 + q * 16) ^ ((row & 7) << 4)));
        #pragma unroll
        for (int nf = 0; nf < 8; ++nf) {
            bf16x8 b = *(const bf16x8*)(pW + PO_WE + (((ks * 8 + nf) * 64) + lane) * 8);
            acc[nf] = __builtin_amdgcn_mfma_f32_16x16x32_bf16(a, b, acc[nf], 0, 0, 0);
        }
    }
    #pragma unroll
    for (int nf = 0; nf < 8; ++nf) {
        int col = nf * 16 + l15;
        float bias = bev[col];
        #pragma unroll
        for (int r = 0; r < 4; ++r) {
            int e = e0 + w * 16 + q * 4 + r;
            eo[(size_t)e * CC + col] = ftanh(acc[nf][r] + bias);
        }
    }
}

extern "C" void kernel_launch(void* const* d_in, const int* in_sizes, int n_in,
                              void* d_out, int out_size, void* d_ws, size_t ws_size,
                              hipStream_t stream) {
    const float* x   = (const float*)d_in[0];
    const int*   ei  = (const int*)d_in[1];
    const float* ea  = (const float*)d_in[2];
    const float* Wf1 = (const float*)d_in[4];
    const float* bf1 = (const float*)d_in[5];
    const float* Wf2 = (const float*)d_in[6];
    const float* bf2 = (const float*)d_in[7];
    const float* Wl1 = (const float*)d_in[8];
    const float* Wl2 = (const float*)d_in[9];
    const float* bl2 = (const float*)d_in[10];
    const float* Wl3 = (const float*)d_in[11];
    const float* bl3 = (const float*)d_in[12];
    const float* We  = (const float*)d_in[13];
    const float* be  = (const float*)d_in[14];

    float* xo = (float*)d_out;                 // [N, C] final
    float* eo = xo + (size_t)NN * CC;          // [E, C] final

    // region reuse (sequential lifetimes, fully rewritten each call):
    //   h    bf16 [N,256] p-order in the xo region (dead before k3 writes xo)
    //   ea_s/col_s/row_s/agg carved from the TAIL of the eo region
    //   (all dead before k4 writes eo; k3 reads agg before k4 runs)
    short* h    = (short*)xo;                                  // 25.6 MB
    char*  top  = (char*)d_out + (size_t)out_size * sizeof(float);
    short* ea_s = (short*)(top - (size_t)NE * ECH * 2);        // 76.8 MB
    int*   col_s = (int*)((char*)ea_s - (size_t)NE * 4);       // 2.4 MB
    int*   row_s = (int*)((char*)col_s - (size_t)NE * 4);      // 2.4 MB
    float* agg  = (float*)((char*)row_s - (size_t)NN * NFF * 4); // 51.2 MB

    // ws: [packed weights 384KB][cnt N][offw N][bsum 256]
    short* pW    = (short*)d_ws;
    int* cnt     = (int*)((char*)d_ws + 393216);
    int* offw    = cnt + NN;
    int* bsum    = offw + NN;

    const int NB = (NN + 255) / 256;

    kpack<<<P_TOT / 256, 256, 0, stream>>>(Wf1, Wf2, We, Wl1, Wl2, Wl3, pW);
    k0_zero2<<<1024, 256, 0, stream>>>(agg, (long)NN * NFF / 4, (float*)cnt, NN / 4);
    k_cnt<<<(NE + 255) / 256, 256, 0, stream>>>(ei, cnt);
    k_scan1<<<NB, 256, 0, stream>>>(cnt, offw, bsum);
    k_scan2<<<1, 256, 0, stream>>>(bsum, NB);
    k_scan3<<<NB, 256, 0, stream>>>(offw, bsum);
    k_scatter<<<(NE + 255) / 256, 256, 0, stream>>>(ei, ea, offw, ea_s, col_s, row_s);
    k1_h<<<(NN + 31) / 32, 256, 0, stream>>>(x, pW, h);
    k2b_agg<<<NE / 64, 256, 0, stream>>>(ea_s, col_s, row_s, pW, bf1, bf2, h, agg);
    k3_node<<<(NN + 31) / 32, 256, 0, stream>>>(agg, pW, bl2, bl3, x, xo);
    k4_mfma<<<NE / 64, 256, 0, stream>>>(ea, ei, xo, pW, be, eo);
}